// Round 15
// baseline (78.654 us; speedup 1.0000x reference)
//
#include <hip/hip_runtime.h>
#include <utility>

// reference == inverse(M M^T + EPS*I) per pixel, M = x[b,:,:,h,w]^T (16x64)
// x: [B=4, C=64, K=16, H=128, W=128] f32 ; out: [B,H,W,16,16] f32
// Fused, 128 px/block, 512 blocks, 256 threads (4 waves) — round-13 shell:
//   wave wv -> (G = wv&1: pair group, ph = wv>>1: pixel half), px = ph*64+lane
//   phase 1: gram via global_load_lds dbuf; chunk = 4c x 16k x 128px = 32 KB
//            (16 barrier-drain events instead of 32; 512 B bursts per instr).
//   phase 2: acc[68] -> tri[136][131] (+EPS diag)
//   phase 3: G==0 waves: tri -> REGISTER Cholesky -> L^-1 -> M^T M -> tri
//   phase 4: vectorized gather-store: thread = element-quad, dwordx4 stores
// LDS: union{stage 2x32KB, tri 71.3KB} = 71.3KB -> 2 blocks/CU, 2 waves/SIMD.

#define EPSR 1e-6f
#define TS2 131                    // tri row stride; 131 mod 32 = 3 (bank spread)

__device__ __host__ constexpr int rowof(int t) {
    int i = 0;
    while ((i + 1) * (i + 2) / 2 <= t) ++i;
    return i;
}
__device__ __host__ constexpr int colof(int t) { return t - rowof(t) * (rowof(t) + 1) / 2; }

__device__ __forceinline__ constexpr int tidx(int i, int j) {  // i >= j
    return i * (i + 1) / 2 + j;
}

#define GLOAD_LDS16(gp, lp)                                                       \
    __builtin_amdgcn_global_load_lds(                                             \
        (const __attribute__((address_space(1))) void*)(gp),                      \
        (__attribute__((address_space(3))) void*)(lp), 16, 0, 0)

// ---------------- pair-split template machinery (68/group) ----------------

template<int P>
__device__ __forceinline__ void fma_pair(const float (&m)[16], float& a) {
    a = fmaf(m[rowof(P)], m[colof(P)], a);
}

template<int G, int... TT>
__device__ __forceinline__ void fma_group(const float (&m)[16], float (&acc)[68],
                                          std::integer_sequence<int, TT...>) {
    (fma_pair<G * 68 + TT>(m, acc[TT]), ...);
}

template<int G>
__device__ __forceinline__ void chunk_fma4(const float* __restrict__ buf, int px,
                                           float (&acc)[68]) {
    #pragma unroll
    for (int crel = 0; crel < 4; ++crel) {
        float m[16];
        #pragma unroll
        for (int k = 0; k < 16; ++k) m[k] = buf[crel * 2048 + k * 128 + px];
        fma_group<G>(m, acc, std::make_integer_sequence<int, 68>{});
    }
}

template<int P>
__device__ __forceinline__ void store_tri_pair(float* __restrict__ tri, int px, float v) {
    constexpr bool diag = (rowof(P) == colof(P));
    tri[P * TS2 + px] = diag ? (v + EPSR) : v;
}

template<int G, int... TT>
__device__ __forceinline__ void store_tri_group(float* __restrict__ tri, int px,
                                                const float (&acc)[68],
                                                std::integer_sequence<int, TT...>) {
    (store_tri_pair<G * 68 + TT>(tri, px, acc[TT]), ...);
}

// ---------------- fused kernel ----------------

union SMem {
    float stage[2][8192];      // 2 x 32 KB: [crel(0..3)*2048 + k*128 + px]
    float tri[136 * TS2];      // 71.3 KB; row = pair index, col = pixel
};

__global__ __launch_bounds__(256, 2)
void fused_gram_inv(const float* __restrict__ x, float* __restrict__ out) {
    __shared__ __align__(16) SMem sm;

    const int tid = threadIdx.x;
    const int lane = tid & 63;
    const int wv = tid >> 6;                  // 0..3
    const int G = wv & 1;                     // pair group (0: pairs 0-67, 1: 68-135)
    const int ph = wv >> 1;                   // pixel half (0: px 0-63, 1: px 64-127)
    const int px = ph * 64 + lane;            // this thread's pixel
    const int p0 = blockIdx.x * 128;
    const int b = blockIdx.x >> 7;            // 128 blocks per batch
    const int hw0 = p0 & 16383;

    // staging src: lane l covers k-row (l>>5), px (l&31)*4..+3  (16 B/lane ->
    // one instr = 2 k-rows x 128 px = 1 KB lane-linear, 512 B contiguous/row)
    const float* gbase = x + (size_t)b * 16777216 + hw0
                           + (size_t)(lane >> 5) * 16384 + (size_t)(lane & 31) * 4;

    float acc[68];
    #pragma unroll
    for (int t = 0; t < 68; ++t) acc[t] = 0.0f;

    // chunk t = channels [4t, 4t+4); wave wv stages crel = wv (16k x 128px = 8 KB,
    // 8 instrs, instr q covers k-rows {2q, 2q+1})
    auto STAGE = [&](int bufi, int c0) {
        const float* gp = gbase + (size_t)(c0 + wv) * 262144;
        #pragma unroll
        for (int q = 0; q < 8; ++q) {
            GLOAD_LDS16(gp + (size_t)(q * 2) * 16384,
                        &sm.stage[bufi][wv * 2048 + (q * 2) * 128]);
        }
    };

    // ---- phase 1: gram, dbuf pipeline (16 chunks of 4 c) ----
    STAGE(0, 0);
    for (int t = 0; t < 16; ++t) {
        __syncthreads();                              // vmcnt(0) drain + barrier
        if (t < 15) STAGE((t + 1) & 1, 4 * (t + 1));  // prefetch next chunk
        const float* buf = sm.stage[t & 1];
        if (G == 0) chunk_fma4<0>(buf, px, acc);
        else        chunk_fma4<1>(buf, px, acc);
    }
    __syncthreads();   // all stage reads done before aliasing stage as tri

    // ---- phase 2: acc -> tri (+EPS on diag); disjoint (rows G, cols ph) ----
    if (G == 0) store_tri_group<0>(sm.tri, px, acc, std::make_integer_sequence<int, 68>{});
    else        store_tri_group<1>(sm.tri, px, acc, std::make_integer_sequence<int, 68>{});
    __syncthreads();

    // ---- phase 3: G==0 waves, lane = own px, REGISTER inversion ----
    if (G == 0) {
        float s[136];
        #pragma unroll
        for (int t = 0; t < 136; ++t) s[t] = sm.tri[t * TS2 + px];

        // Cholesky in place: off-diag = L[i][j], diag = 1/L[j][j]
        #pragma unroll
        for (int j = 0; j < 16; ++j) {
            float d = s[tidx(j, j)];
            #pragma unroll
            for (int q = 0; q < j; ++q) d = fmaf(-s[tidx(j, q)], s[tidx(j, q)], d);
            const float invd = 1.0f / sqrtf(d);
            s[tidx(j, j)] = invd;
            #pragma unroll
            for (int i = j + 1; i < 16; ++i) {
                float v = s[tidx(i, j)];
                #pragma unroll
                for (int q = 0; q < j; ++q) v = fmaf(-s[tidx(i, q)], s[tidx(j, q)], v);
                s[tidx(i, j)] = v * invd;
            }
        }

        // M = L^{-1} in place (diag already inverted)
        #pragma unroll
        for (int j = 0; j < 16; ++j) {
            #pragma unroll
            for (int i = j + 1; i < 16; ++i) {
                float sum = s[tidx(i, j)] * s[tidx(j, j)];
                #pragma unroll
                for (int q = j + 1; q < i; ++q)
                    sum = fmaf(s[tidx(i, q)], s[tidx(q, j)], sum);
                s[tidx(i, j)] = -s[tidx(i, i)] * sum;
            }
        }

        // A^{-1} = M^T M in place
        #pragma unroll
        for (int j = 0; j < 16; ++j) {
            #pragma unroll
            for (int i = j; i < 16; ++i) {
                float sum = 0.0f;
                #pragma unroll
                for (int q = i; q < 16; ++q)
                    sum = fmaf(s[tidx(q, i)], s[tidx(q, j)], sum);
                s[tidx(i, j)] = sum;
            }
        }

        // writeback
        #pragma unroll
        for (int t = 0; t < 136; ++t) sm.tri[t * TS2 + px] = s[t];
    }
    __syncthreads();

    // ---- phase 4: vectorized gather-store ----
    // thread t: element quad e0 = 4*(t&63) (same output row i), a-quarter t>>6;
    // per a: 4 LDS b32 gathers + one global_store_dwordx4, 1 KB coalesced lines.
    const int e0 = (tid & 63) * 4;
    const int aq = tid >> 6;            // 0..3
    const int i0 = e0 >> 4;
    int trow[4];
    #pragma unroll
    for (int r = 0; r < 4; ++r) {
        const int j = (e0 + r) & 15;
        const int hi = i0 > j ? i0 : j;
        const int lo = i0 + j - hi;
        trow[r] = hi * (hi + 1) / 2 + lo;
    }
    float* gout = out + (size_t)p0 * 256;
    #pragma unroll 8
    for (int a = aq * 32; a < aq * 32 + 32; ++a) {
        float4 v;
        v.x = sm.tri[trow[0] * TS2 + a];
        v.y = sm.tri[trow[1] * TS2 + a];
        v.z = sm.tri[trow[2] * TS2 + a];
        v.w = sm.tri[trow[3] * TS2 + a];
        *reinterpret_cast<float4*>(gout + (size_t)a * 256 + e0) = v;
    }
}

extern "C" void kernel_launch(void* const* d_in, const int* in_sizes, int n_in,
                              void* d_out, int out_size, void* d_ws, size_t ws_size,
                              hipStream_t stream) {
    const float* x = (const float*)d_in[0];
    float* out = (float*)d_out;
    hipLaunchKernelGGL(fused_gram_inv, dim3(512), dim3(256), 0, stream, x, out);
}

// Round 16
// 73.144 us; speedup vs baseline: 1.0753x; 1.0753x over previous
//
#include <hip/hip_runtime.h>
#include <utility>

// reference == inverse(M M^T + EPS*I) per pixel, M = x[b,:,:,h,w]^T (16x64)
// x: [B=4, C=64, K=16, H=128, W=128] f32 ; out: [B,H,W,16,16] f32
// Fused, 128 px/block, 512 blocks, 256 threads (4 waves) — round-13 structure,
// single change: 4-buffer counted-vmcnt staging pipeline (3 chunks in flight,
// no per-chunk vmcnt(0) drain; occupancy unchanged: 64KB stage unions tri).
//   wave wv -> (G = wv&1: pair group, ph = wv>>1: pixel half), px = ph*64+lane
//   phase 1: gram via global_load_lds, chunk = 2c x 16k x 128px = 16 KB x 4 bufs
//   phase 2: acc[68] -> tri[136][131] (+EPS diag)
//   phase 3: G==0 waves: tri -> REGISTER Cholesky -> L^-1 -> M^T M -> tri
//   phase 4: r13 gather-store (thread = element, loop 128 px, coalesced)
// LDS: union{stage 4x16KB, tri 71.3KB} = 71.3KB -> 2 blocks/CU, 2 waves/SIMD.

#define EPSR 1e-6f
#define TS2 131                    // tri row stride; 131 mod 32 = 3 (bank spread)

__device__ __host__ constexpr int rowof(int t) {
    int i = 0;
    while ((i + 1) * (i + 2) / 2 <= t) ++i;
    return i;
}
__device__ __host__ constexpr int colof(int t) { return t - rowof(t) * (rowof(t) + 1) / 2; }

__device__ __forceinline__ constexpr int tidx(int i, int j) {  // i >= j
    return i * (i + 1) / 2 + j;
}

#define GLOAD_LDS16(gp, lp)                                                       \
    __builtin_amdgcn_global_load_lds(                                             \
        (const __attribute__((address_space(1))) void*)(gp),                      \
        (__attribute__((address_space(3))) void*)(lp), 16, 0, 0)

// ---------------- pair-split template machinery (68/group) ----------------

template<int P>
__device__ __forceinline__ void fma_pair(const float (&m)[16], float& a) {
    a = fmaf(m[rowof(P)], m[colof(P)], a);
}

template<int G, int... TT>
__device__ __forceinline__ void fma_group(const float (&m)[16], float (&acc)[68],
                                          std::integer_sequence<int, TT...>) {
    (fma_pair<G * 68 + TT>(m, acc[TT]), ...);
}

template<int G>
__device__ __forceinline__ void chunk_fma2(const float* __restrict__ buf, int px,
                                           float (&acc)[68]) {
    #pragma unroll
    for (int cs = 0; cs < 2; ++cs) {
        float m[16];
        #pragma unroll
        for (int k = 0; k < 16; ++k) m[k] = buf[cs * 2048 + k * 128 + px];
        fma_group<G>(m, acc, std::make_integer_sequence<int, 68>{});
    }
}

template<int P>
__device__ __forceinline__ void store_tri_pair(float* __restrict__ tri, int px, float v) {
    constexpr bool diag = (rowof(P) == colof(P));
    tri[P * TS2 + px] = diag ? (v + EPSR) : v;
}

template<int G, int... TT>
__device__ __forceinline__ void store_tri_group(float* __restrict__ tri, int px,
                                                const float (&acc)[68],
                                                std::integer_sequence<int, TT...>) {
    (store_tri_pair<G * 68 + TT>(tri, px, acc[TT]), ...);
}

// ---------------- fused kernel ----------------

union SMem {
    float stage[4][4096];      // 4 x 16 KB: [c'(0..1)*2048 + k*128 + px]
    float tri[136 * TS2];      // 71.3 KB; row = pair index, col = pixel
};

__global__ __launch_bounds__(256, 2)
void fused_gram_inv(const float* __restrict__ x, float* __restrict__ out) {
    __shared__ __align__(16) SMem sm;

    const int tid = threadIdx.x;
    const int lane = tid & 63;
    const int wv = tid >> 6;                  // 0..3
    const int G = wv & 1;                     // pair group (0: pairs 0-67, 1: 68-135)
    const int ph = wv >> 1;                   // pixel half (0: px 0-63, 1: px 64-127)
    const int px = ph * 64 + lane;            // this thread's pixel
    const int p0 = blockIdx.x * 128;
    const int b = blockIdx.x >> 7;            // 128 blocks per batch
    const int hw0 = p0 & 16383;

    // staging src: lane l covers k-row (l>>5), px (l&31)*4..+3  (16 B/lane,
    // one instr = 2 k-rows x 128 px = 1 KB, lane-linear in LDS)
    const float* gbase = x + (size_t)b * 16777216 + hw0
                           + (size_t)(lane >> 5) * 16384 + (size_t)(lane & 31) * 4;

    float acc[68];
    #pragma unroll
    for (int t = 0; t < 68; ++t) acc[t] = 0.0f;

    // chunk t = channels {2t, 2t+1}; wave (ph,G) stages c' = ph, k in [8G, 8G+8)
    // (4 instrs x 1 KB per wave)
    auto STAGE = [&](int bufi, int t) {
        const float* gp = gbase + (size_t)(2 * t + ph) * 262144
                                + (size_t)(G * 8) * 16384;
        #pragma unroll
        for (int q = 0; q < 4; ++q) {
            GLOAD_LDS16(gp + (size_t)(q * 2) * 16384,
                        &sm.stage[bufi][ph * 2048 + (G * 8 + q * 2) * 128]);
        }
    };

    // ---- phase 1: gram, 4-buffer counted-vmcnt pipeline (32 chunks of 2 c) ----
    STAGE(0, 0);
    STAGE(1, 1);
    STAGE(2, 2);                               // 12 loads outstanding / wave
    for (int t = 0; t < 30; ++t) {
        // chunk t landed when this wave's outstanding <= 8 (chunks t+1,t+2 fly)
        asm volatile("s_waitcnt vmcnt(8)" ::: "memory");
        __builtin_amdgcn_s_barrier();
        if (t < 29) STAGE((t + 3) & 3, t + 3);
        const float* buf = sm.stage[t & 3];
        if (G == 0) chunk_fma2<0>(buf, px, acc);
        else        chunk_fma2<1>(buf, px, acc);
    }
    {   // t = 30: only chunk 31's 4 loads may remain in flight
        asm volatile("s_waitcnt vmcnt(4)" ::: "memory");
        __builtin_amdgcn_s_barrier();
        const float* buf = sm.stage[30 & 3];
        if (G == 0) chunk_fma2<0>(buf, px, acc);
        else        chunk_fma2<1>(buf, px, acc);
    }
    {   // t = 31: full drain
        asm volatile("s_waitcnt vmcnt(0)" ::: "memory");
        __builtin_amdgcn_s_barrier();
        const float* buf = sm.stage[31 & 3];
        if (G == 0) chunk_fma2<0>(buf, px, acc);
        else        chunk_fma2<1>(buf, px, acc);
    }
    __syncthreads();   // all stage reads done before aliasing stage as tri

    // ---- phase 2: acc -> tri (+EPS on diag); disjoint (rows G, cols ph) ----
    if (G == 0) store_tri_group<0>(sm.tri, px, acc, std::make_integer_sequence<int, 68>{});
    else        store_tri_group<1>(sm.tri, px, acc, std::make_integer_sequence<int, 68>{});
    __syncthreads();

    // ---- phase 3: G==0 waves, lane = own px, REGISTER inversion ----
    if (G == 0) {
        float s[136];
        #pragma unroll
        for (int t = 0; t < 136; ++t) s[t] = sm.tri[t * TS2 + px];

        // Cholesky in place: off-diag = L[i][j], diag = 1/L[j][j]
        #pragma unroll
        for (int j = 0; j < 16; ++j) {
            float d = s[tidx(j, j)];
            #pragma unroll
            for (int q = 0; q < j; ++q) d = fmaf(-s[tidx(j, q)], s[tidx(j, q)], d);
            const float invd = 1.0f / sqrtf(d);
            s[tidx(j, j)] = invd;
            #pragma unroll
            for (int i = j + 1; i < 16; ++i) {
                float v = s[tidx(i, j)];
                #pragma unroll
                for (int q = 0; q < j; ++q) v = fmaf(-s[tidx(i, q)], s[tidx(j, q)], v);
                s[tidx(i, j)] = v * invd;
            }
        }

        // M = L^{-1} in place (diag already inverted)
        #pragma unroll
        for (int j = 0; j < 16; ++j) {
            #pragma unroll
            for (int i = j + 1; i < 16; ++i) {
                float sum = s[tidx(i, j)] * s[tidx(j, j)];
                #pragma unroll
                for (int q = j + 1; q < i; ++q)
                    sum = fmaf(s[tidx(i, q)], s[tidx(q, j)], sum);
                s[tidx(i, j)] = -s[tidx(i, i)] * sum;
            }
        }

        // A^{-1} = M^T M in place
        #pragma unroll
        for (int j = 0; j < 16; ++j) {
            #pragma unroll
            for (int i = j; i < 16; ++i) {
                float sum = 0.0f;
                #pragma unroll
                for (int q = i; q < 16; ++q)
                    sum = fmaf(s[tidx(q, i)], s[tidx(q, j)], sum);
                s[tidx(i, j)] = sum;
            }
        }

        // writeback
        #pragma unroll
        for (int t = 0; t < 136; ++t) sm.tri[t * TS2 + px] = s[t];
    }
    __syncthreads();

    // ---- phase 4: gather-store, thread = output element e, loop 128 px ----
    const int e = tid;                  // 0..255 -> (i,j)
    const int i = e >> 4, j = e & 15;
    const int hi = i > j ? i : j;
    const int lo = i + j - hi;
    const int trow = hi * (hi + 1) / 2 + lo;
    float* gout = out + (size_t)p0 * 256;
    #pragma unroll 8
    for (int a = 0; a < 128; ++a) {
        gout[(size_t)a * 256 + e] = sm.tri[trow * TS2 + a];
    }
}

extern "C" void kernel_launch(void* const* d_in, const int* in_sizes, int n_in,
                              void* d_out, int out_size, void* d_ws, size_t ws_size,
                              hipStream_t stream) {
    const float* x = (const float*)d_in[0];
    float* out = (float*)d_out;
    hipLaunchKernelGGL(fused_gram_inv, dim3(512), dim3(256), 0, stream, x, out);
}

// Round 17
// 70.614 us; speedup vs baseline: 1.1139x; 1.0358x over previous
//
#include <hip/hip_runtime.h>
#include <utility>

// reference == inverse(M M^T + EPS*I) per pixel, M = x[b,:,:,h,w]^T (16x64)
// x: [B=4, C=64, K=16, H=128, W=128] f32 ; out: [B,H,W,16,16] f32
// Round-13 structure, single change: chunk 2c -> 4c (32 KB), so
//   - 16 barrier-drain events instead of 32
//   - 8 staging instrs/wave/chunk instead of 4 (2x memory-level parallelism)
// Fused, 128 px/block, 512 blocks, 256 threads (4 waves):
//   wave wv -> (G = wv&1: pair group, ph = wv>>1: pixel half), px = ph*64+lane
//   phase 1: gram via global_load_lds dbuf; chunk = 4c x 16k x 128px = 32 KB
//   phase 2: acc[68] -> tri[136][131] (+EPS diag)
//   phase 3: G==0 waves: tri -> REGISTER Cholesky -> L^-1 -> M^T M -> tri
//   phase 4: r13 gather-store (thread = element, loop 128 px, coalesced)
// LDS: union{stage 2x32KB, tri 71.3KB} = 71.3KB -> 2 blocks/CU, 2 waves/SIMD.

#define EPSR 1e-6f
#define TS2 131                    // tri row stride; 131 mod 32 = 3 (bank spread)

__device__ __host__ constexpr int rowof(int t) {
    int i = 0;
    while ((i + 1) * (i + 2) / 2 <= t) ++i;
    return i;
}
__device__ __host__ constexpr int colof(int t) { return t - rowof(t) * (rowof(t) + 1) / 2; }

__device__ __forceinline__ constexpr int tidx(int i, int j) {  // i >= j
    return i * (i + 1) / 2 + j;
}

#define GLOAD_LDS16(gp, lp)                                                       \
    __builtin_amdgcn_global_load_lds(                                             \
        (const __attribute__((address_space(1))) void*)(gp),                      \
        (__attribute__((address_space(3))) void*)(lp), 16, 0, 0)

// ---------------- pair-split template machinery (68/group) ----------------

template<int P>
__device__ __forceinline__ void fma_pair(const float (&m)[16], float& a) {
    a = fmaf(m[rowof(P)], m[colof(P)], a);
}

template<int G, int... TT>
__device__ __forceinline__ void fma_group(const float (&m)[16], float (&acc)[68],
                                          std::integer_sequence<int, TT...>) {
    (fma_pair<G * 68 + TT>(m, acc[TT]), ...);
}

template<int G>
__device__ __forceinline__ void chunk_fma4(const float* __restrict__ buf, int px,
                                           float (&acc)[68]) {
    #pragma unroll
    for (int crel = 0; crel < 4; ++crel) {
        float m[16];
        #pragma unroll
        for (int k = 0; k < 16; ++k) m[k] = buf[crel * 2048 + k * 128 + px];
        fma_group<G>(m, acc, std::make_integer_sequence<int, 68>{});
    }
}

template<int P>
__device__ __forceinline__ void store_tri_pair(float* __restrict__ tri, int px, float v) {
    constexpr bool diag = (rowof(P) == colof(P));
    tri[P * TS2 + px] = diag ? (v + EPSR) : v;
}

template<int G, int... TT>
__device__ __forceinline__ void store_tri_group(float* __restrict__ tri, int px,
                                                const float (&acc)[68],
                                                std::integer_sequence<int, TT...>) {
    (store_tri_pair<G * 68 + TT>(tri, px, acc[TT]), ...);
}

// ---------------- fused kernel ----------------

union SMem {
    float stage[2][8192];      // 2 x 32 KB: [crel(0..3)*2048 + k*128 + px]
    float tri[136 * TS2];      // 71.3 KB; row = pair index, col = pixel
};

__global__ __launch_bounds__(256, 2)
void fused_gram_inv(const float* __restrict__ x, float* __restrict__ out) {
    __shared__ __align__(16) SMem sm;

    const int tid = threadIdx.x;
    const int lane = tid & 63;
    const int wv = tid >> 6;                  // 0..3
    const int G = wv & 1;                     // pair group (0: pairs 0-67, 1: 68-135)
    const int ph = wv >> 1;                   // pixel half (0: px 0-63, 1: px 64-127)
    const int px = ph * 64 + lane;            // this thread's pixel
    const int p0 = blockIdx.x * 128;
    const int b = blockIdx.x >> 7;            // 128 blocks per batch
    const int hw0 = p0 & 16383;

    // staging src: lane l covers k-row (l>>5), px (l&31)*4..+3  (16 B/lane ->
    // one instr = 2 k-rows x 128 px = 1 KB lane-linear, 512 B contiguous/row)
    const float* gbase = x + (size_t)b * 16777216 + hw0
                           + (size_t)(lane >> 5) * 16384 + (size_t)(lane & 31) * 4;

    float acc[68];
    #pragma unroll
    for (int t = 0; t < 68; ++t) acc[t] = 0.0f;

    // chunk t = channels [4t, 4t+4); wave wv stages crel = wv (16k x 128px = 8 KB,
    // 8 instrs, instr q covers k-rows {2q, 2q+1})
    auto STAGE = [&](int bufi, int c0) {
        const float* gp = gbase + (size_t)(c0 + wv) * 262144;
        #pragma unroll
        for (int q = 0; q < 8; ++q) {
            GLOAD_LDS16(gp + (size_t)(q * 2) * 16384,
                        &sm.stage[bufi][wv * 2048 + (q * 2) * 128]);
        }
    };

    // ---- phase 1: gram, dbuf pipeline (16 chunks of 4 c) ----
    STAGE(0, 0);
    for (int t = 0; t < 16; ++t) {
        __syncthreads();                              // vmcnt(0) drain + barrier
        if (t < 15) STAGE((t + 1) & 1, 4 * (t + 1));  // prefetch next chunk
        const float* buf = sm.stage[t & 1];
        if (G == 0) chunk_fma4<0>(buf, px, acc);
        else        chunk_fma4<1>(buf, px, acc);
    }
    __syncthreads();   // all stage reads done before aliasing stage as tri

    // ---- phase 2: acc -> tri (+EPS on diag); disjoint (rows G, cols ph) ----
    if (G == 0) store_tri_group<0>(sm.tri, px, acc, std::make_integer_sequence<int, 68>{});
    else        store_tri_group<1>(sm.tri, px, acc, std::make_integer_sequence<int, 68>{});
    __syncthreads();

    // ---- phase 3: G==0 waves, lane = own px, REGISTER inversion ----
    if (G == 0) {
        float s[136];
        #pragma unroll
        for (int t = 0; t < 136; ++t) s[t] = sm.tri[t * TS2 + px];

        // Cholesky in place: off-diag = L[i][j], diag = 1/L[j][j]
        #pragma unroll
        for (int j = 0; j < 16; ++j) {
            float d = s[tidx(j, j)];
            #pragma unroll
            for (int q = 0; q < j; ++q) d = fmaf(-s[tidx(j, q)], s[tidx(j, q)], d);
            const float invd = 1.0f / sqrtf(d);
            s[tidx(j, j)] = invd;
            #pragma unroll
            for (int i = j + 1; i < 16; ++i) {
                float v = s[tidx(i, j)];
                #pragma unroll
                for (int q = 0; q < j; ++q) v = fmaf(-s[tidx(i, q)], s[tidx(j, q)], v);
                s[tidx(i, j)] = v * invd;
            }
        }

        // M = L^{-1} in place (diag already inverted)
        #pragma unroll
        for (int j = 0; j < 16; ++j) {
            #pragma unroll
            for (int i = j + 1; i < 16; ++i) {
                float sum = s[tidx(i, j)] * s[tidx(j, j)];
                #pragma unroll
                for (int q = j + 1; q < i; ++q)
                    sum = fmaf(s[tidx(i, q)], s[tidx(q, j)], sum);
                s[tidx(i, j)] = -s[tidx(i, i)] * sum;
            }
        }

        // A^{-1} = M^T M in place
        #pragma unroll
        for (int j = 0; j < 16; ++j) {
            #pragma unroll
            for (int i = j; i < 16; ++i) {
                float sum = 0.0f;
                #pragma unroll
                for (int q = i; q < 16; ++q)
                    sum = fmaf(s[tidx(q, i)], s[tidx(q, j)], sum);
                s[tidx(i, j)] = sum;
            }
        }

        // writeback
        #pragma unroll
        for (int t = 0; t < 136; ++t) sm.tri[t * TS2 + px] = s[t];
    }
    __syncthreads();

    // ---- phase 4: gather-store, thread = output element e, loop 128 px ----
    const int e = tid;                  // 0..255 -> (i,j)
    const int i = e >> 4, j = e & 15;
    const int hi = i > j ? i : j;
    const int lo = i + j - hi;
    const int trow = hi * (hi + 1) / 2 + lo;
    float* gout = out + (size_t)p0 * 256;
    #pragma unroll 8
    for (int a = 0; a < 128; ++a) {
        gout[(size_t)a * 256 + e] = sm.tri[trow * TS2 + a];
    }
}

extern "C" void kernel_launch(void* const* d_in, const int* in_sizes, int n_in,
                              void* d_out, int out_size, void* d_ws, size_t ws_size,
                              hipStream_t stream) {
    const float* x = (const float*)d_in[0];
    float* out = (float*)d_out;
    hipLaunchKernelGGL(fused_gram_inv, dim3(512), dim3(256), 0, stream, x, out);
}